// Round 6
// baseline (2619.370 us; speedup 1.0000x reference)
//
#include <hip/hip_runtime.h>

#define NN 262144
#define HH 128
#define EE 16
#define MAXD 12
#define CAP 8192          // per-(depth,category) capacity; expected ~5041
#define GBLK 2048         // 8 blocks/CU co-resident via __launch_bounds__(128,4)
#define NTHR 128
#define CLR 16            // cap: left+right children per slot per depth (Poisson(0.08))
#define CH 8              // cap: head children per slot per depth (Poisson(0.02))
#define GB_GATHER 1280    // phase-B split: [0,GB_GATHER) gather, rest lep

struct Prm {
    const float* x_in;
    const int*   parents;
    const int*   depths;
    const int*   states;
    const float* pef;
    const float* plef;
    const float *mW1, *mb1, *mW2, *mb2;
    const float *pW1, *pb1, *pW2, *pb2;
    const float *eW1, *eb1, *eW2, *eb2;
    float* x;
    // zeroed-per-launch region:
    int *cntB;            // [36]
    int *cntAL, *cntAH;   // [12] each
    int *go;              // [1]
    int *arrive;          // [GBLK*4] stride-4
    int *cntCLR, *cntCH;  // [12*CAP] each
    int *allocL, *allocH; // [NN] bitmask of depths allocated
    int *maskL, *maskH;   // [NN] bit d: has left/head child at depth d
    // persistent (rebuilt each launch before use):
    int *listL, *listR, *listHd;       // [12*CAP]
    int *activeL12, *activeH12;        // [12*CAP]
    unsigned short *slotL12, *slotH12; // [12*NN]
    int *childLR, *childH;             // [12*CAP*CLR], [12*CAP*CH]
    float *left_c, *right_c, *lepOut;  // [CAP*HH]
};

// --- agent-scope relaxed (sc1) accessors: bypass L1/L2, coherent at MALL ----
__device__ __forceinline__ float ldc(const float* p) {
    return __hip_atomic_load((const float*)p, __ATOMIC_RELAXED, __HIP_MEMORY_SCOPE_AGENT);
}
__device__ __forceinline__ void stc(float* p, float v) {
    __hip_atomic_store(p, v, __ATOMIC_RELAXED, __HIP_MEMORY_SCOPE_AGENT);
}
__device__ __forceinline__ int ldi(const int* p) {
    return __hip_atomic_load(p, __ATOMIC_RELAXED, __HIP_MEMORY_SCOPE_AGENT);
}
__device__ __forceinline__ void sti(int* p, int v) {
    __hip_atomic_store(p, v, __ATOMIC_RELAXED, __HIP_MEMORY_SCOPE_AGENT);
}

// --- flag-based grid barrier: no contended RMW; fences only when requested --
__device__ __forceinline__ void gbar(const Prm& prm, int round, bool fence) {
    __syncthreads();                       // drains each wave's vmem before arrive
    if (threadIdx.x == 0) {
        if (fence) __builtin_amdgcn_fence(__ATOMIC_RELEASE, "agent");
        sti(&prm.arrive[blockIdx.x * 4], round);
    }
    if (blockIdx.x == 0) {
        for (int i = threadIdx.x; i < GBLK; i += NTHR)
            while (ldi(&prm.arrive[i * 4]) < round) __builtin_amdgcn_s_sleep(8);
        __syncthreads();
        if (threadIdx.x == 0) sti(prm.go, round);
    } else if (threadIdx.x == 0) {
        while (ldi(prm.go) < round) __builtin_amdgcn_s_sleep(16);
    }
    if (fence && threadIdx.x == 0)
        __builtin_amdgcn_fence(__ATOMIC_ACQUIRE, "agent");
    __syncthreads();
}

// ---------------------------------------------------------------------------
// 8-row 2-layer MLP, 128 threads (thread j = output column j), no split-K.
// MODE 0 merger: in=[left_c[g],right_c[g],pef[p]] -> x[p]
// MODE 1 lep:    in=[x[c],plef[c]]               -> lepOut[g]
// MODE 2 lem:    in=[x[p], sum lepOut children]  -> x[p] if !maskL bit
template <int MODE, int INDIM>
__device__ void mlp8(const Prm& prm, int d, int g0, int n,
                     const int* __restrict__ rowList,
                     const float* __restrict__ W1, const float* __restrict__ b1,
                     const float* __restrict__ W2, const float* __restrict__ b2,
                     float* sh_raw) {
    const int tid = threadIdx.x;
    float (*sh_in)[INDIM] = (float (*)[INDIM])sh_raw;
    float (*sh_h)[HH]     = (float (*)[HH])(sh_raw + 8 * INDIM);
    const int dd = d - 1;

    __syncthreads();   // protect LDS reuse across phases/tasks

    if (MODE == 2) {
        #pragma unroll
        for (int r = 0; r < 8; ++r) {
            int g = g0 + r;
            float xv = 0.f, mh = 0.f;
            if (g < n) {
                int p = rowList[g];
                xv = ldc(&prm.x[(size_t)p * HH + tid]);
                int cb = dd * CAP + g;
                int cnt = prm.cntCH[cb];
                if (cnt > CH) cnt = CH;
                for (int i = 0; i < cnt; ++i) {
                    int pos = prm.childH[cb * CH + i];
                    mh += ldc(&prm.lepOut[(size_t)pos * HH + tid]);
                }
            }
            sh_in[r][tid] = xv;
            sh_in[r][HH + tid] = mh;
        }
    } else {
        for (int idx = tid; idx < 8 * INDIM; idx += NTHR) {
            int r = idx / INDIM, k = idx - r * INDIM;
            int g = g0 + r;
            float v = 0.f;
            if (g < n) {
                if (MODE == 0) {
                    if (k < HH)           v = ldc(&prm.left_c [(size_t)g * HH + k]);
                    else if (k < 2 * HH)  v = ldc(&prm.right_c[(size_t)g * HH + (k - HH)]);
                    else                  v = prm.pef[(size_t)rowList[g] * EE + (k - 2 * HH)];
                } else {
                    int c = rowList[g];
                    if (k < HH) v = ldc(&prm.x[(size_t)c * HH + k]);
                    else        v = prm.plef[(size_t)c * EE + (k - HH)];
                }
            }
            sh_in[r][k] = v;
        }
    }
    __syncthreads();

    float acc[8];
    #pragma unroll
    for (int r = 0; r < 8; ++r) acc[r] = 0.f;
    for (int kk = 0; kk < INDIM; kk += 4) {
        float w0 = W1[(size_t)(kk + 0) * HH + tid];
        float w1 = W1[(size_t)(kk + 1) * HH + tid];
        float w2 = W1[(size_t)(kk + 2) * HH + tid];
        float w3 = W1[(size_t)(kk + 3) * HH + tid];
        #pragma unroll
        for (int r = 0; r < 8; ++r) {
            float4 v = *(const float4*)&sh_in[r][kk];
            acc[r] += v.x * w0 + v.y * w1 + v.z * w2 + v.w * w3;
        }
    }
    float bb = b1[tid];
    #pragma unroll
    for (int r = 0; r < 8; ++r) sh_h[r][tid] = fmaxf(acc[r] + bb, 0.f);
    __syncthreads();

    float acc2[8];
    #pragma unroll
    for (int r = 0; r < 8; ++r) acc2[r] = 0.f;
    for (int kk = 0; kk < HH; kk += 4) {
        float w0 = W2[(size_t)(kk + 0) * HH + tid];
        float w1 = W2[(size_t)(kk + 1) * HH + tid];
        float w2 = W2[(size_t)(kk + 2) * HH + tid];
        float w3 = W2[(size_t)(kk + 3) * HH + tid];
        #pragma unroll
        for (int r = 0; r < 8; ++r) {
            float4 v = *(const float4*)&sh_h[r][kk];
            acc2[r] += v.x * w0 + v.y * w1 + v.z * w2 + v.w * w3;
        }
    }
    float bb2 = b2[tid];
    for (int r = 0; r < 8; ++r) {
        int g = g0 + r;
        if (g >= n) break;
        float val = acc2[r] + bb2;
        if (MODE == 0) {
            stc(&prm.x[(size_t)rowList[g] * HH + tid], val);
        } else if (MODE == 1) {
            stc(&prm.lepOut[(size_t)g * HH + tid], val);
        } else {
            int p = rowList[g];
            if (!((prm.maskL[p] >> d) & 1))        // parents_mask priority
                stc(&prm.x[(size_t)p * HH + tid], val);
        }
    }
}

// ---------------------------------------------------------------------------
__global__ __launch_bounds__(NTHR, 4)
void persist(Prm prm) {
    const int bid = blockIdx.x, tid = threadIdx.x;
    const int gtid = bid * NTHR + tid;
    const int gsize = GBLK * NTHR;     // 262144
    int rnd = 0;

    __shared__ float sh_raw[8 * (2 * HH + EE) + 8 * HH];
    __shared__ int lcnt[36], lbase[36];

    // ---- P0a: copy x (sc1 stores), bucket by (depth,cat), build masks -----
    for (int i = gtid; i < NN * HH; i += gsize) stc(&prm.x[i], prm.x_in[i]);

    if (tid < 36) lcnt[tid] = 0;
    __syncthreads();
    {
        int i = bid * NTHR + tid;      // NN/GBLK == NTHR: exactly one node
        int dep = prm.depths[i], st = prm.states[i];
        int b = -1, rank = 0;
        if (dep >= 1 && (st == 0 || st == 1 || st == 3)) {
            int cat = (st == 3) ? 2 : st;
            b = (dep - 1) * 3 + cat;
            rank = atomicAdd(&lcnt[b], 1);
            int p = prm.parents[i];
            if (cat == 0)      atomicOr(&prm.maskL[p], 1 << dep);
            else if (cat == 2) atomicOr(&prm.maskH[p], 1 << dep);
        }
        __syncthreads();
        if (tid < 36 && lcnt[tid] > 0) lbase[tid] = atomicAdd(&prm.cntB[tid], lcnt[tid]);
        __syncthreads();
        if (b >= 0) {
            int idx = lbase[b] + rank;
            if (idx < CAP) {
                int dd = b / 3, cat = b - dd * 3;
                int* lst = (cat == 0) ? prm.listL : (cat == 1) ? prm.listR : prm.listHd;
                lst[dd * CAP + idx] = i;
            }
        }
    }
    gbar(prm, ++rnd, true);

    // ---- P0b: allocate slots for left-parents and head-parents, all depths
    for (int t = gtid; t < 12 * CAP; t += gsize) {
        int dd = t / CAP, g = t - dd * CAP;
        if (g < min(prm.cntB[dd * 3 + 0], CAP)) {
            int c = prm.listL[dd * CAP + g];
            int p = prm.parents[c];
            int old = atomicOr(&prm.allocL[p], 1 << dd);
            if (!((old >> dd) & 1)) {
                int s = atomicAdd(&prm.cntAL[dd], 1);
                if (s < CAP) {
                    prm.slotL12[(size_t)dd * NN + p] = (unsigned short)s;
                    prm.activeL12[dd * CAP + s] = p;
                }
            }
        }
        if (g < min(prm.cntB[dd * 3 + 2], CAP)) {
            int c = prm.listHd[dd * CAP + g];
            int p = prm.parents[c];
            int old = atomicOr(&prm.allocH[p], 1 << dd);
            if (!((old >> dd) & 1)) {
                int s = atomicAdd(&prm.cntAH[dd], 1);
                if (s < CAP) {
                    prm.slotH12[(size_t)dd * NN + p] = (unsigned short)s;
                    prm.activeH12[dd * CAP + s] = p;
                }
            }
        }
    }
    gbar(prm, ++rnd, true);

    // ---- P0c: append children to per-slot lists ---------------------------
    for (int t = gtid; t < 12 * CAP; t += gsize) {
        int dd = t / CAP, g = t - dd * CAP;
        int d1 = dd + 1;
        if (g < min(prm.cntB[dd * 3 + 0], CAP)) {          // lefts (tag 0)
            int c = prm.listL[dd * CAP + g];
            int s = prm.slotL12[(size_t)dd * NN + prm.parents[c]];
            int idx = atomicAdd(&prm.cntCLR[dd * CAP + s], 1);
            if (idx < CLR) prm.childLR[(size_t)(dd * CAP + s) * CLR + idx] = c * 2;
        }
        if (g < min(prm.cntB[dd * 3 + 1], CAP)) {          // rights (tag 1)
            int c = prm.listR[dd * CAP + g];
            int p = prm.parents[c];
            if ((prm.maskL[p] >> d1) & 1) {                // only if parent has a left
                int s = prm.slotL12[(size_t)dd * NN + p];
                int idx = atomicAdd(&prm.cntCLR[dd * CAP + s], 1);
                if (idx < CLR) prm.childLR[(size_t)(dd * CAP + s) * CLR + idx] = c * 2 + 1;
            }
        }
        if (g < min(prm.cntB[dd * 3 + 2], CAP)) {          // heads: store POSITION g
            int c = prm.listHd[dd * CAP + g];
            int s = prm.slotH12[(size_t)dd * NN + prm.parents[c]];
            int idx = atomicAdd(&prm.cntCH[dd * CAP + s], 1);
            if (idx < CH) prm.childH[(size_t)(dd * CAP + s) * CH + idx] = g;
        }
    }
    gbar(prm, ++rnd, true);

    // ---- depth loop: 2 fence-free barriers per depth ----------------------
    for (int d = MAXD; d >= 1; --d) {
        const int dd = d - 1;
        int nAL = min(prm.cntAL[dd], CAP);
        int nAH = min(prm.cntAH[dd], CAP);
        int nH  = min(prm.cntB[dd * 3 + 2], CAP);

        // Phase B (reads x only): gather left/right sums || lep MLP
        if (bid < GB_GATHER) {
            int w = tid >> 6, lane = tid & 63;
            for (int s = bid * 2 + w; s < nAL; s += GB_GATHER * 2) {
                int cb = dd * CAP + s;
                int cnt = prm.cntCLR[cb];
                if (cnt > CLR) cnt = CLR;
                float l0 = 0.f, l1 = 0.f, r0 = 0.f, r1 = 0.f;
                for (int i = 0; i < cnt; ++i) {
                    int e = prm.childLR[(size_t)cb * CLR + i];
                    const float* xr = prm.x + (size_t)(e >> 1) * HH + lane * 2;
                    float a = ldc(xr), b = ldc(xr + 1);
                    if (e & 1) { r0 += a; r1 += b; } else { l0 += a; l1 += b; }
                }
                float* L = prm.left_c  + (size_t)s * HH + lane * 2;
                float* R = prm.right_c + (size_t)s * HH + lane * 2;
                stc(L, l0); stc(L + 1, l1); stc(R, r0); stc(R + 1, r1);
            }
        } else {
            int nrb = (nH + 7) / 8;
            for (int t = bid - GB_GATHER; t < nrb; t += GBLK - GB_GATHER)
                mlp8<1, HH + EE>(prm, d, t * 8, nH, prm.listHd + dd * CAP,
                                 prm.pW1, prm.pb1, prm.pW2, prm.pb2, sh_raw);
        }
        gbar(prm, ++rnd, false);

        // Phase C (writes x): merger || lem. lem's read of x[p] races merger's
        // write only when maskL bit is set -> lem output discarded there.
        {
            int mRB = (nAL + 7) / 8, lRB = (nAH + 7) / 8;
            for (int t = bid; t < mRB + lRB; t += GBLK) {
                if (t < mRB)
                    mlp8<0, 2 * HH + EE>(prm, d, t * 8, nAL, prm.activeL12 + dd * CAP,
                                         prm.mW1, prm.mb1, prm.mW2, prm.mb2, sh_raw);
                else
                    mlp8<2, 2 * HH>(prm, d, (t - mRB) * 8, nAH, prm.activeH12 + dd * CAP,
                                    prm.eW1, prm.eb1, prm.eW2, prm.eb2, sh_raw);
            }
        }
        gbar(prm, ++rnd, false);
    }
}

// ---------------------------------------------------------------------------
extern "C" void kernel_launch(void* const* d_in, const int* in_sizes, int n_in,
                              void* d_out, int out_size, void* d_ws, size_t ws_size,
                              hipStream_t stream) {
    Prm prm;
    prm.x_in    = (const float*)d_in[0];
    const int* edge = (const int*)d_in[1];
    prm.depths  = (const int*)d_in[2];
    prm.states  = (const int*)d_in[3];
    prm.pef     = (const float*)d_in[4];
    prm.plef    = (const float*)d_in[5];
    prm.mW1 = (const float*)d_in[6];  prm.mb1 = (const float*)d_in[7];
    prm.mW2 = (const float*)d_in[8];  prm.mb2 = (const float*)d_in[9];
    prm.pW1 = (const float*)d_in[10]; prm.pb1 = (const float*)d_in[11];
    prm.pW2 = (const float*)d_in[12]; prm.pb2 = (const float*)d_in[13];
    prm.eW1 = (const float*)d_in[14]; prm.eb1 = (const float*)d_in[15];
    prm.eW2 = (const float*)d_in[16]; prm.eb2 = (const float*)d_in[17];
    prm.x = (float*)d_out;
    prm.parents = edge + NN;

    char* w = (char*)d_ws;
    auto alloc = [&](size_t bytes) {
        void* p = (void*)w;
        w += (bytes + 255) & ~(size_t)255;
        return p;
    };
    // ---- zeroed region (one contiguous memset) ----
    char* zbase = w;
    prm.cntB   = (int*)alloc(64 * 4);
    prm.cntAL  = (int*)alloc(16 * 4);
    prm.cntAH  = (int*)alloc(16 * 4);
    prm.go     = (int*)alloc(64 * 4);
    prm.arrive = (int*)alloc((size_t)GBLK * 4 * 4);
    prm.cntCLR = (int*)alloc((size_t)12 * CAP * 4);
    prm.cntCH  = (int*)alloc((size_t)12 * CAP * 4);
    prm.allocL = (int*)alloc((size_t)NN * 4);
    prm.allocH = (int*)alloc((size_t)NN * 4);
    prm.maskL  = (int*)alloc((size_t)NN * 4);
    prm.maskH  = (int*)alloc((size_t)NN * 4);
    size_t zbytes = (size_t)(w - zbase);
    // ---- non-zeroed (fully rebuilt before use each launch) ----
    prm.listL     = (int*)alloc((size_t)12 * CAP * 4);
    prm.listR     = (int*)alloc((size_t)12 * CAP * 4);
    prm.listHd    = (int*)alloc((size_t)12 * CAP * 4);
    prm.activeL12 = (int*)alloc((size_t)12 * CAP * 4);
    prm.activeH12 = (int*)alloc((size_t)12 * CAP * 4);
    prm.slotL12   = (unsigned short*)alloc((size_t)12 * NN * 2);
    prm.slotH12   = (unsigned short*)alloc((size_t)12 * NN * 2);
    prm.childLR   = (int*)alloc((size_t)12 * CAP * CLR * 4);
    prm.childH    = (int*)alloc((size_t)12 * CAP * CH * 4);
    prm.left_c    = (float*)alloc((size_t)CAP * HH * 4);
    prm.right_c   = (float*)alloc((size_t)CAP * HH * 4);
    prm.lepOut    = (float*)alloc((size_t)CAP * HH * 4);

    hipMemsetAsync(zbase, 0, zbytes, stream);

    persist<<<dim3(GBLK), dim3(NTHR), 0, stream>>>(prm);
}

// Round 7
// 2026.951 us; speedup vs baseline: 1.2923x; 1.2923x over previous
//
#include <hip/hip_runtime.h>

#define NN 262144
#define HH 128
#define EE 16
#define MAXD 12
#define CAP 8192          // per-(depth,category) capacity; expected ~5041
#define CLR 16            // cap: left+right children per slot per depth
#define CH 8              // cap: head children per slot per depth
#define G_GATHER 640      // S1: blocks [0,G_GATHER) gather, rest lep MLP

struct Prm {
    const float* x_in;
    const int*   parents;
    const int*   depths;
    const int*   states;
    const float* pef;
    const float* plef;
    const float *mW1, *mb1, *mW2, *mb2;
    const float *pW1, *pb1, *pW2, *pb2;
    const float *eW1, *eb1, *eW2, *eb2;
    float* x;
    // zeroed-per-launch:
    int *cntB;            // [36]
    int *cntAL, *cntAH;   // [12] each
    int *cntCLR, *cntCH;  // [12*CAP] each
    int *allocL, *allocH; // [NN] bitmask: slot allocated at depth dd
    int *maskL, *maskH;   // [NN] bit d: has left/head child at depth d
    // rebuilt each launch before use:
    int *listL, *listR, *listHd;       // [12*CAP]
    int *activeL12, *activeH12;        // [12*CAP]
    unsigned short *slotL12, *slotH12; // [12*NN]
    int *childLR, *childH;             // [12*CAP*CLR], [12*CAP*CH]
    float *left_c, *right_c, *lepOut;  // [CAP*HH]
};

// ---------------------------------------------------------------------------
// setup A: copy x, bucket nodes by (depth, cat), build has-left/has-head masks
__global__ __launch_bounds__(128)
void setupA(Prm prm) {
    __shared__ int lcnt[36], lbase[36];
    const int tid = threadIdx.x;
    const int gtid = blockIdx.x * 128 + tid;       // == node id (2048*128 = NN)
    const int gsz = gridDim.x * 128;

    const float4* src = (const float4*)prm.x_in;
    float4* dst = (float4*)prm.x;
    for (int i = gtid; i < NN * HH / 4; i += gsz) dst[i] = src[i];

    if (tid < 36) lcnt[tid] = 0;
    __syncthreads();
    int dep = prm.depths[gtid], st = prm.states[gtid];
    int b = -1, rank = 0;
    if (dep >= 1 && (st == 0 || st == 1 || st == 3)) {
        int cat = (st == 3) ? 2 : st;
        b = (dep - 1) * 3 + cat;
        rank = atomicAdd(&lcnt[b], 1);
        int p = prm.parents[gtid];
        if (cat == 0)      atomicOr(&prm.maskL[p], 1 << dep);
        else if (cat == 2) atomicOr(&prm.maskH[p], 1 << dep);
    }
    __syncthreads();
    if (tid < 36 && lcnt[tid] > 0) lbase[tid] = atomicAdd(&prm.cntB[tid], lcnt[tid]);
    __syncthreads();
    if (b >= 0) {
        int idx = lbase[b] + rank;
        if (idx < CAP) {
            int dd = b / 3, cat = b - dd * 3;
            int* lst = (cat == 0) ? prm.listL : (cat == 1) ? prm.listR : prm.listHd;
            lst[dd * CAP + idx] = gtid;
        }
    }
}

// ---------------------------------------------------------------------------
// setup B: allocate compact slots for left-parents / head-parents, all depths
__global__ __launch_bounds__(256)
void setupB(Prm prm) {
    for (int t = blockIdx.x * 256 + threadIdx.x; t < 12 * CAP; t += gridDim.x * 256) {
        int dd = t / CAP, g = t - dd * CAP;
        if (g < min(prm.cntB[dd * 3 + 0], CAP)) {
            int p = prm.parents[prm.listL[dd * CAP + g]];
            int old = atomicOr(&prm.allocL[p], 1 << dd);
            if (!((old >> dd) & 1)) {
                int s = atomicAdd(&prm.cntAL[dd], 1);
                if (s < CAP) {
                    prm.slotL12[(size_t)dd * NN + p] = (unsigned short)s;
                    prm.activeL12[dd * CAP + s] = p;
                }
            }
        }
        if (g < min(prm.cntB[dd * 3 + 2], CAP)) {
            int p = prm.parents[prm.listHd[dd * CAP + g]];
            int old = atomicOr(&prm.allocH[p], 1 << dd);
            if (!((old >> dd) & 1)) {
                int s = atomicAdd(&prm.cntAH[dd], 1);
                if (s < CAP) {
                    prm.slotH12[(size_t)dd * NN + p] = (unsigned short)s;
                    prm.activeH12[dd * CAP + s] = p;
                }
            }
        }
    }
}

// ---------------------------------------------------------------------------
// setup C: append children to per-slot lists
__global__ __launch_bounds__(256)
void setupC(Prm prm) {
    for (int t = blockIdx.x * 256 + threadIdx.x; t < 12 * CAP; t += gridDim.x * 256) {
        int dd = t / CAP, g = t - dd * CAP;
        int d1 = dd + 1;
        if (g < min(prm.cntB[dd * 3 + 0], CAP)) {            // lefts (tag 0)
            int c = prm.listL[dd * CAP + g];
            int s = prm.slotL12[(size_t)dd * NN + prm.parents[c]];
            int idx = atomicAdd(&prm.cntCLR[dd * CAP + s], 1);
            if (idx < CLR) prm.childLR[(size_t)(dd * CAP + s) * CLR + idx] = c * 2;
        }
        if (g < min(prm.cntB[dd * 3 + 1], CAP)) {            // rights (tag 1)
            int c = prm.listR[dd * CAP + g];
            int p = prm.parents[c];
            if ((prm.maskL[p] >> d1) & 1) {                  // only if parent has a left
                int s = prm.slotL12[(size_t)dd * NN + p];
                int idx = atomicAdd(&prm.cntCLR[dd * CAP + s], 1);
                if (idx < CLR) prm.childLR[(size_t)(dd * CAP + s) * CLR + idx] = c * 2 + 1;
            }
        }
        if (g < min(prm.cntB[dd * 3 + 2], CAP)) {            // heads: store POSITION g
            int c = prm.listHd[dd * CAP + g];
            int s = prm.slotH12[(size_t)dd * NN + prm.parents[c]];
            int idx = atomicAdd(&prm.cntCH[dd * CAP + s], 1);
            if (idx < CH) prm.childH[(size_t)(dd * CAP + s) * CH + idx] = g;
        }
    }
}

// ---------------------------------------------------------------------------
// 8-row 2-layer MLP, 128 threads (thread j = output column j).
// MODE 0 merger: in=[left_c[g],right_c[g],pef[p]] -> x[p]
// MODE 1 lep:    in=[x[c],plef[c]]                -> lepOut[g]
// MODE 2 lem:    in=[x[p], sum lepOut children]   -> x[p] if !maskL bit
template <int MODE, int INDIM>
__device__ void mlp8(const Prm& prm, int d, int g0, int n,
                     const int* __restrict__ rowList,
                     const float* __restrict__ W1, const float* __restrict__ b1,
                     const float* __restrict__ W2, const float* __restrict__ b2,
                     float* sh_raw) {
    const int tid = threadIdx.x;
    float (*sh_in)[INDIM] = (float (*)[INDIM])sh_raw;
    float (*sh_h)[HH]     = (float (*)[HH])(sh_raw + 8 * INDIM);
    const int dd = d - 1;

    if (MODE == 2) {
        #pragma unroll
        for (int r = 0; r < 8; ++r) {
            int g = g0 + r;
            float xv = 0.f, mh = 0.f;
            if (g < n) {
                int p = rowList[g];
                xv = prm.x[(size_t)p * HH + tid];
                int cb = dd * CAP + g;
                int cnt = prm.cntCH[cb];
                if (cnt > CH) cnt = CH;
                for (int i = 0; i < cnt; ++i) {
                    int pos = prm.childH[cb * CH + i];
                    mh += prm.lepOut[(size_t)pos * HH + tid];
                }
            }
            sh_in[r][tid] = xv;
            sh_in[r][HH + tid] = mh;
        }
    } else {
        for (int idx = tid; idx < 8 * INDIM; idx += 128) {
            int r = idx / INDIM, k = idx - r * INDIM;
            int g = g0 + r;
            float v = 0.f;
            if (g < n) {
                if (MODE == 0) {
                    if (k < HH)           v = prm.left_c [(size_t)g * HH + k];
                    else if (k < 2 * HH)  v = prm.right_c[(size_t)g * HH + (k - HH)];
                    else                  v = prm.pef[(size_t)rowList[g] * EE + (k - 2 * HH)];
                } else {
                    int c = rowList[g];
                    if (k < HH) v = prm.x[(size_t)c * HH + k];
                    else        v = prm.plef[(size_t)c * EE + (k - HH)];
                }
            }
            sh_in[r][k] = v;
        }
    }
    __syncthreads();

    float acc[8];
    #pragma unroll
    for (int r = 0; r < 8; ++r) acc[r] = 0.f;
    for (int kk = 0; kk < INDIM; kk += 4) {
        float w0 = W1[(size_t)(kk + 0) * HH + tid];
        float w1 = W1[(size_t)(kk + 1) * HH + tid];
        float w2 = W1[(size_t)(kk + 2) * HH + tid];
        float w3 = W1[(size_t)(kk + 3) * HH + tid];
        #pragma unroll
        for (int r = 0; r < 8; ++r) {
            float4 v = *(const float4*)&sh_in[r][kk];
            acc[r] += v.x * w0 + v.y * w1 + v.z * w2 + v.w * w3;
        }
    }
    float bb = b1[tid];
    #pragma unroll
    for (int r = 0; r < 8; ++r) sh_h[r][tid] = fmaxf(acc[r] + bb, 0.f);
    __syncthreads();

    float acc2[8];
    #pragma unroll
    for (int r = 0; r < 8; ++r) acc2[r] = 0.f;
    for (int kk = 0; kk < HH; kk += 4) {
        float w0 = W2[(size_t)(kk + 0) * HH + tid];
        float w1 = W2[(size_t)(kk + 1) * HH + tid];
        float w2 = W2[(size_t)(kk + 2) * HH + tid];
        float w3 = W2[(size_t)(kk + 3) * HH + tid];
        #pragma unroll
        for (int r = 0; r < 8; ++r) {
            float4 v = *(const float4*)&sh_h[r][kk];
            acc2[r] += v.x * w0 + v.y * w1 + v.z * w2 + v.w * w3;
        }
    }
    float bb2 = b2[tid];
    for (int r = 0; r < 8; ++r) {
        int g = g0 + r;
        if (g >= n) break;
        float val = acc2[r] + bb2;
        if (MODE == 0) {
            prm.x[(size_t)rowList[g] * HH + tid] = val;
        } else if (MODE == 1) {
            prm.lepOut[(size_t)g * HH + tid] = val;
        } else {
            int p = rowList[g];
            if (!((prm.maskL[p] >> d) & 1))        // parents_mask priority
                prm.x[(size_t)p * HH + tid] = val;
        }
    }
}

// ---------------------------------------------------------------------------
// S1 (reads x only): gather left/right child sums [0,G_GATHER) || lep MLP rest
__global__ __launch_bounds__(128)
void s1_kernel(Prm prm, int d) {
    const int dd = d - 1;
    const int bid = blockIdx.x, tid = threadIdx.x;
    if (bid < G_GATHER) {
        int nAL = min(prm.cntAL[dd], CAP);
        int w = tid >> 6, lane = tid & 63;
        for (int s = bid * 2 + w; s < nAL; s += G_GATHER * 2) {
            int cb = dd * CAP + s;
            int cnt = prm.cntCLR[cb];
            if (cnt > CLR) cnt = CLR;
            float l0 = 0.f, l1 = 0.f, r0 = 0.f, r1 = 0.f;
            for (int i = 0; i < cnt; ++i) {
                int e = prm.childLR[(size_t)cb * CLR + i];
                const float2 v = *(const float2*)(prm.x + (size_t)(e >> 1) * HH + lane * 2);
                if (e & 1) { r0 += v.x; r1 += v.y; } else { l0 += v.x; l1 += v.y; }
            }
            *(float2*)(prm.left_c  + (size_t)s * HH + lane * 2) = make_float2(l0, l1);
            *(float2*)(prm.right_c + (size_t)s * HH + lane * 2) = make_float2(r0, r1);
        }
    } else {
        __shared__ float sh_raw[8 * (HH + EE) + 8 * HH];
        int nH = min(prm.cntB[dd * 3 + 2], CAP);
        int g0 = (bid - G_GATHER) * 8;
        if (g0 < nH)
            mlp8<1, HH + EE>(prm, d, g0, nH, prm.listHd + dd * CAP,
                             prm.pW1, prm.pb1, prm.pW2, prm.pb2, sh_raw);
    }
}

// ---------------------------------------------------------------------------
// S2 (writes x): merger [0,CAP/8) || lem [CAP/8, 2*CAP/8). lem reads x[p] only
// where merger doesn't write (or where its own output is discarded) — safe.
__global__ __launch_bounds__(128)
void s2_kernel(Prm prm, int d) {
    const int dd = d - 1;
    const int bid = blockIdx.x;
    __shared__ float sh_raw[8 * (2 * HH + EE) + 8 * HH];
    if (bid < CAP / 8) {
        int nAL = min(prm.cntAL[dd], CAP);
        int g0 = bid * 8;
        if (g0 < nAL)
            mlp8<0, 2 * HH + EE>(prm, d, g0, nAL, prm.activeL12 + dd * CAP,
                                 prm.mW1, prm.mb1, prm.mW2, prm.mb2, sh_raw);
    } else {
        int nAH = min(prm.cntAH[dd], CAP);
        int g0 = (bid - CAP / 8) * 8;
        if (g0 < nAH)
            mlp8<2, 2 * HH>(prm, d, g0, nAH, prm.activeH12 + dd * CAP,
                            prm.eW1, prm.eb1, prm.eW2, prm.eb2, sh_raw);
    }
}

// ---------------------------------------------------------------------------
extern "C" void kernel_launch(void* const* d_in, const int* in_sizes, int n_in,
                              void* d_out, int out_size, void* d_ws, size_t ws_size,
                              hipStream_t stream) {
    Prm prm;
    prm.x_in    = (const float*)d_in[0];
    const int* edge = (const int*)d_in[1];
    prm.depths  = (const int*)d_in[2];
    prm.states  = (const int*)d_in[3];
    prm.pef     = (const float*)d_in[4];
    prm.plef    = (const float*)d_in[5];
    prm.mW1 = (const float*)d_in[6];  prm.mb1 = (const float*)d_in[7];
    prm.mW2 = (const float*)d_in[8];  prm.mb2 = (const float*)d_in[9];
    prm.pW1 = (const float*)d_in[10]; prm.pb1 = (const float*)d_in[11];
    prm.pW2 = (const float*)d_in[12]; prm.pb2 = (const float*)d_in[13];
    prm.eW1 = (const float*)d_in[14]; prm.eb1 = (const float*)d_in[15];
    prm.eW2 = (const float*)d_in[16]; prm.eb2 = (const float*)d_in[17];
    prm.x = (float*)d_out;
    prm.parents = edge + NN;

    char* w = (char*)d_ws;
    auto alloc = [&](size_t bytes) {
        void* p = (void*)w;
        w += (bytes + 255) & ~(size_t)255;
        return p;
    };
    // ---- zeroed region (one contiguous memset) ----
    char* zbase = w;
    prm.cntB   = (int*)alloc(64 * 4);
    prm.cntAL  = (int*)alloc(16 * 4);
    prm.cntAH  = (int*)alloc(16 * 4);
    prm.cntCLR = (int*)alloc((size_t)12 * CAP * 4);
    prm.cntCH  = (int*)alloc((size_t)12 * CAP * 4);
    prm.allocL = (int*)alloc((size_t)NN * 4);
    prm.allocH = (int*)alloc((size_t)NN * 4);
    prm.maskL  = (int*)alloc((size_t)NN * 4);
    prm.maskH  = (int*)alloc((size_t)NN * 4);
    size_t zbytes = (size_t)(w - zbase);
    // ---- non-zeroed (fully rebuilt before use each launch) ----
    prm.listL     = (int*)alloc((size_t)12 * CAP * 4);
    prm.listR     = (int*)alloc((size_t)12 * CAP * 4);
    prm.listHd    = (int*)alloc((size_t)12 * CAP * 4);
    prm.activeL12 = (int*)alloc((size_t)12 * CAP * 4);
    prm.activeH12 = (int*)alloc((size_t)12 * CAP * 4);
    prm.slotL12   = (unsigned short*)alloc((size_t)12 * NN * 2);
    prm.slotH12   = (unsigned short*)alloc((size_t)12 * NN * 2);
    prm.childLR   = (int*)alloc((size_t)12 * CAP * CLR * 4);
    prm.childH    = (int*)alloc((size_t)12 * CAP * CH * 4);
    prm.left_c    = (float*)alloc((size_t)CAP * HH * 4);
    prm.right_c   = (float*)alloc((size_t)CAP * HH * 4);
    prm.lepOut    = (float*)alloc((size_t)CAP * HH * 4);

    hipMemsetAsync(zbase, 0, zbytes, stream);

    setupA<<<NN / 128, 128, 0, stream>>>(prm);
    setupB<<<384, 256, 0, stream>>>(prm);
    setupC<<<384, 256, 0, stream>>>(prm);

    for (int d = MAXD; d >= 1; --d) {
        s1_kernel<<<G_GATHER + CAP / 8, 128, 0, stream>>>(prm, d);
        s2_kernel<<<2 * (CAP / 8), 128, 0, stream>>>(prm, d);
    }
}

// Round 8
// 954.681 us; speedup vs baseline: 2.7437x; 2.1232x over previous
//
#include <hip/hip_runtime.h>

#define NN 262144
#define HH 128
#define EE 16
#define MAXD 12
#define CAP 8192          // per-(depth,category) capacity; expected ~5041
#define CLR 16            // cap: left+right children per slot per depth
#define CH 8              // cap: head children per slot per depth
#define G_GATHER 640      // S1: blocks [0,G_GATHER) gather, rest lep MLP

struct Prm {
    const float* x_in;
    const int*   parents;
    const int*   depths;
    const int*   states;
    const float* pef;
    const float* plef;
    const float *mW1, *mb1, *mW2, *mb2;
    const float *pW1, *pb1, *pW2, *pb2;
    const float *eW1, *eb1, *eW2, *eb2;
    float* x;
    // zeroed-per-launch:
    int *cntB;            // [36]
    int *cntCLR, *cntCH;  // [12*CAP] each
    int *maskL, *maskH;   // [NN] bit d: has left/head child at depth d
    // memset 0x7f per launch:
    int *firstL, *firstH; // [12*NN] min list-position of p's child (the "slot")
    // rebuilt each launch before use:
    int *listL, *listR, *listHd;       // [12*CAP]
    int *childLR, *childH;             // [12*CAP*CLR], [12*CAP*CH]
    float *left_c, *right_c, *lepOut;  // [CAP*HH]
};

// ---------------------------------------------------------------------------
// setup A: copy x, bucket nodes by (depth, cat), build masks, min-position
// slot assignment (scattered atomicMin — no hot counter lines).
__global__ __launch_bounds__(128)
void setupA(Prm prm) {
    __shared__ int lcnt[36], lbase[36];
    const int tid = threadIdx.x;
    const int gtid = blockIdx.x * 128 + tid;       // == node id (2048*128 = NN)
    const int gsz = gridDim.x * 128;

    const float4* src = (const float4*)prm.x_in;
    float4* dst = (float4*)prm.x;
    for (int i = gtid; i < NN * HH / 4; i += gsz) dst[i] = src[i];

    if (tid < 36) lcnt[tid] = 0;
    __syncthreads();
    int dep = prm.depths[gtid], st = prm.states[gtid];
    int b = -1, rank = 0, p = 0;
    if (dep >= 1 && (st == 0 || st == 1 || st == 3)) {
        int cat = (st == 3) ? 2 : st;
        b = (dep - 1) * 3 + cat;
        rank = atomicAdd(&lcnt[b], 1);
        p = prm.parents[gtid];
        if (cat == 0)      atomicOr(&prm.maskL[p], 1 << dep);
        else if (cat == 2) atomicOr(&prm.maskH[p], 1 << dep);
    }
    __syncthreads();
    if (tid < 36 && lcnt[tid] > 0) lbase[tid] = atomicAdd(&prm.cntB[tid], lcnt[tid]);
    __syncthreads();
    if (b >= 0) {
        int idx = lbase[b] + rank;
        if (idx < CAP) {
            int dd = b / 3, cat = b - dd * 3;
            if (cat == 0) {
                prm.listL[dd * CAP + idx] = gtid;
                atomicMin(&prm.firstL[(size_t)dd * NN + p], idx);   // slot = min pos
            } else if (cat == 1) {
                prm.listR[dd * CAP + idx] = gtid;
            } else {
                prm.listHd[dd * CAP + idx] = gtid;
                atomicMin(&prm.firstH[(size_t)dd * NN + p], idx);
            }
        }
    }
}

// ---------------------------------------------------------------------------
// setup C: append children to per-slot lists (scattered atomics only)
__global__ __launch_bounds__(256)
void setupC(Prm prm) {
    for (int t = blockIdx.x * 256 + threadIdx.x; t < 12 * CAP; t += gridDim.x * 256) {
        int dd = t / CAP, g = t - dd * CAP;
        int d1 = dd + 1;
        if (g < min(prm.cntB[dd * 3 + 0], CAP)) {            // lefts (tag 0)
            int c = prm.listL[dd * CAP + g];
            int s = prm.firstL[(size_t)dd * NN + prm.parents[c]];
            int idx = atomicAdd(&prm.cntCLR[dd * CAP + s], 1);
            if (idx < CLR) prm.childLR[(size_t)(dd * CAP + s) * CLR + idx] = c * 2;
        }
        if (g < min(prm.cntB[dd * 3 + 1], CAP)) {            // rights (tag 1)
            int c = prm.listR[dd * CAP + g];
            int p = prm.parents[c];
            if ((prm.maskL[p] >> d1) & 1) {                  // only if parent has a left
                int s = prm.firstL[(size_t)dd * NN + p];
                int idx = atomicAdd(&prm.cntCLR[dd * CAP + s], 1);
                if (idx < CLR) prm.childLR[(size_t)(dd * CAP + s) * CLR + idx] = c * 2 + 1;
            }
        }
        if (g < min(prm.cntB[dd * 3 + 2], CAP)) {            // heads: store POSITION g
            int c = prm.listHd[dd * CAP + g];
            int s = prm.firstH[(size_t)dd * NN + prm.parents[c]];
            int idx = atomicAdd(&prm.cntCH[dd * CAP + s], 1);
            if (idx < CH) prm.childH[(size_t)(dd * CAP + s) * CH + idx] = g;
        }
    }
}

// ---------------------------------------------------------------------------
// 8-row 2-layer MLP, 128 threads (thread j = output column j).
// MODE 0 merger: rows=listL (dups ok); in=[left_c[s],right_c[s],pef[p]] -> x[p]
// MODE 1 lep:    rows=listHd; in=[x[c],plef[c]]                         -> lepOut[g]
// MODE 2 lem:    rows=listHd (dups ok); in=[x[p], sum lepOut childH[s]] -> x[p] if !maskL
template <int MODE, int INDIM>
__device__ void mlp8(const Prm& prm, int d, int g0, int n,
                     const int* __restrict__ rowList,
                     const float* __restrict__ W1, const float* __restrict__ b1,
                     const float* __restrict__ W2, const float* __restrict__ b2,
                     float* sh_raw) {
    const int tid = threadIdx.x;
    float (*sh_in)[INDIM] = (float (*)[INDIM])sh_raw;
    float (*sh_h)[HH]     = (float (*)[HH])(sh_raw + 8 * INDIM);
    const int dd = d - 1;

    if (MODE == 0) {
        #pragma unroll
        for (int r = 0; r < 8; ++r) {
            int g = g0 + r;
            float lv = 0.f, rv = 0.f, pv = 0.f;
            if (g < n) {
                int p = prm.parents[rowList[g]];
                int s = prm.firstL[(size_t)dd * NN + p];
                lv = prm.left_c [(size_t)s * HH + tid];
                rv = prm.right_c[(size_t)s * HH + tid];
                if (tid < EE) pv = prm.pef[(size_t)p * EE + tid];
            }
            sh_in[r][tid] = lv;
            sh_in[r][HH + tid] = rv;
            if (tid < EE) sh_in[r][2 * HH + tid] = pv;
        }
    } else if (MODE == 2) {
        #pragma unroll
        for (int r = 0; r < 8; ++r) {
            int g = g0 + r;
            float xv = 0.f, mh = 0.f;
            if (g < n) {
                int p = prm.parents[rowList[g]];
                int s = prm.firstH[(size_t)dd * NN + p];
                xv = prm.x[(size_t)p * HH + tid];
                int cb = dd * CAP + s;
                int cnt = prm.cntCH[cb];
                if (cnt > CH) cnt = CH;
                for (int i = 0; i < cnt; ++i) {
                    int pos = prm.childH[(size_t)cb * CH + i];
                    mh += prm.lepOut[(size_t)pos * HH + tid];
                }
            }
            sh_in[r][tid] = xv;
            sh_in[r][HH + tid] = mh;
        }
    } else {
        for (int idx = tid; idx < 8 * INDIM; idx += 128) {
            int r = idx / INDIM, k = idx - r * INDIM;
            int g = g0 + r;
            float v = 0.f;
            if (g < n) {
                int c = rowList[g];
                if (k < HH) v = prm.x[(size_t)c * HH + k];
                else        v = prm.plef[(size_t)c * EE + (k - HH)];
            }
            sh_in[r][k] = v;
        }
    }
    __syncthreads();

    float acc[8];
    #pragma unroll
    for (int r = 0; r < 8; ++r) acc[r] = 0.f;
    for (int kk = 0; kk < INDIM; kk += 4) {
        float w0 = W1[(size_t)(kk + 0) * HH + tid];
        float w1 = W1[(size_t)(kk + 1) * HH + tid];
        float w2 = W1[(size_t)(kk + 2) * HH + tid];
        float w3 = W1[(size_t)(kk + 3) * HH + tid];
        #pragma unroll
        for (int r = 0; r < 8; ++r) {
            float4 v = *(const float4*)&sh_in[r][kk];
            acc[r] += v.x * w0 + v.y * w1 + v.z * w2 + v.w * w3;
        }
    }
    float bb = b1[tid];
    #pragma unroll
    for (int r = 0; r < 8; ++r) sh_h[r][tid] = fmaxf(acc[r] + bb, 0.f);
    __syncthreads();

    float acc2[8];
    #pragma unroll
    for (int r = 0; r < 8; ++r) acc2[r] = 0.f;
    for (int kk = 0; kk < HH; kk += 4) {
        float w0 = W2[(size_t)(kk + 0) * HH + tid];
        float w1 = W2[(size_t)(kk + 1) * HH + tid];
        float w2 = W2[(size_t)(kk + 2) * HH + tid];
        float w3 = W2[(size_t)(kk + 3) * HH + tid];
        #pragma unroll
        for (int r = 0; r < 8; ++r) {
            float4 v = *(const float4*)&sh_h[r][kk];
            acc2[r] += v.x * w0 + v.y * w1 + v.z * w2 + v.w * w3;
        }
    }
    float bb2 = b2[tid];
    for (int r = 0; r < 8; ++r) {
        int g = g0 + r;
        if (g >= n) break;
        float val = acc2[r] + bb2;
        if (MODE == 0) {
            prm.x[(size_t)prm.parents[rowList[g]] * HH + tid] = val;  // dup rows: same value
        } else if (MODE == 1) {
            prm.lepOut[(size_t)g * HH + tid] = val;
        } else {
            int p = prm.parents[rowList[g]];
            if (!((prm.maskL[p] >> d) & 1))        // parents_mask priority
                prm.x[(size_t)p * HH + tid] = val; // dup rows: same value
        }
    }
}

// ---------------------------------------------------------------------------
// S1 (reads x only): gather left/right child sums [0,G_GATHER) || lep MLP rest
__global__ __launch_bounds__(128)
void s1_kernel(Prm prm, int d) {
    const int dd = d - 1;
    const int bid = blockIdx.x, tid = threadIdx.x;
    if (bid < G_GATHER) {
        int nL = min(prm.cntB[dd * 3 + 0], CAP);
        int w = tid >> 6, lane = tid & 63;
        for (int s = bid * 2 + w; s < nL; s += G_GATHER * 2) {
            int cb = dd * CAP + s;
            int cnt = prm.cntCLR[cb];
            if (cnt > CLR) cnt = CLR;
            float l0 = 0.f, l1 = 0.f, r0 = 0.f, r1 = 0.f;
            for (int i = 0; i < cnt; ++i) {
                int e = prm.childLR[(size_t)cb * CLR + i];
                const float2 v = *(const float2*)(prm.x + (size_t)(e >> 1) * HH + lane * 2);
                if (e & 1) { r0 += v.x; r1 += v.y; } else { l0 += v.x; l1 += v.y; }
            }
            *(float2*)(prm.left_c  + (size_t)s * HH + lane * 2) = make_float2(l0, l1);
            *(float2*)(prm.right_c + (size_t)s * HH + lane * 2) = make_float2(r0, r1);
        }
    } else {
        __shared__ float sh_raw[8 * (HH + EE) + 8 * HH];
        int nH = min(prm.cntB[dd * 3 + 2], CAP);
        int g0 = (bid - G_GATHER) * 8;
        if (g0 < nH)
            mlp8<1, HH + EE>(prm, d, g0, nH, prm.listHd + dd * CAP,
                             prm.pW1, prm.pb1, prm.pW2, prm.pb2, sh_raw);
    }
}

// ---------------------------------------------------------------------------
// S2 (writes x): merger [0,CAP/8) || lem [CAP/8, 2*CAP/8).
// lem reads x[p] racing merger's write only where lem's output is discarded.
__global__ __launch_bounds__(128)
void s2_kernel(Prm prm, int d) {
    const int dd = d - 1;
    const int bid = blockIdx.x;
    __shared__ float sh_raw[8 * (2 * HH + EE) + 8 * HH];
    if (bid < CAP / 8) {
        int nL = min(prm.cntB[dd * 3 + 0], CAP);
        int g0 = bid * 8;
        if (g0 < nL)
            mlp8<0, 2 * HH + EE>(prm, d, g0, nL, prm.listL + dd * CAP,
                                 prm.mW1, prm.mb1, prm.mW2, prm.mb2, sh_raw);
    } else {
        int nH = min(prm.cntB[dd * 3 + 2], CAP);
        int g0 = (bid - CAP / 8) * 8;
        if (g0 < nH)
            mlp8<2, 2 * HH>(prm, d, g0, nH, prm.listHd + dd * CAP,
                            prm.eW1, prm.eb1, prm.eW2, prm.eb2, sh_raw);
    }
}

// ---------------------------------------------------------------------------
extern "C" void kernel_launch(void* const* d_in, const int* in_sizes, int n_in,
                              void* d_out, int out_size, void* d_ws, size_t ws_size,
                              hipStream_t stream) {
    Prm prm;
    prm.x_in    = (const float*)d_in[0];
    const int* edge = (const int*)d_in[1];
    prm.depths  = (const int*)d_in[2];
    prm.states  = (const int*)d_in[3];
    prm.pef     = (const float*)d_in[4];
    prm.plef    = (const float*)d_in[5];
    prm.mW1 = (const float*)d_in[6];  prm.mb1 = (const float*)d_in[7];
    prm.mW2 = (const float*)d_in[8];  prm.mb2 = (const float*)d_in[9];
    prm.pW1 = (const float*)d_in[10]; prm.pb1 = (const float*)d_in[11];
    prm.pW2 = (const float*)d_in[12]; prm.pb2 = (const float*)d_in[13];
    prm.eW1 = (const float*)d_in[14]; prm.eb1 = (const float*)d_in[15];
    prm.eW2 = (const float*)d_in[16]; prm.eb2 = (const float*)d_in[17];
    prm.x = (float*)d_out;
    prm.parents = edge + NN;

    char* w = (char*)d_ws;
    auto alloc = [&](size_t bytes) {
        void* p = (void*)w;
        w += (bytes + 255) & ~(size_t)255;
        return p;
    };
    // ---- zeroed region ----
    char* zbase = w;
    prm.cntB   = (int*)alloc(64 * 4);
    prm.cntCLR = (int*)alloc((size_t)12 * CAP * 4);
    prm.cntCH  = (int*)alloc((size_t)12 * CAP * 4);
    prm.maskL  = (int*)alloc((size_t)NN * 4);
    prm.maskH  = (int*)alloc((size_t)NN * 4);
    size_t zbytes = (size_t)(w - zbase);
    // ---- 0x7f region (atomicMin init) ----
    char* fbase = w;
    prm.firstL = (int*)alloc((size_t)12 * NN * 4);
    prm.firstH = (int*)alloc((size_t)12 * NN * 4);
    size_t fbytes = (size_t)(w - fbase);
    // ---- non-zeroed (fully rebuilt before use each launch) ----
    prm.listL     = (int*)alloc((size_t)12 * CAP * 4);
    prm.listR     = (int*)alloc((size_t)12 * CAP * 4);
    prm.listHd    = (int*)alloc((size_t)12 * CAP * 4);
    prm.childLR   = (int*)alloc((size_t)12 * CAP * CLR * 4);
    prm.childH    = (int*)alloc((size_t)12 * CAP * CH * 4);
    prm.left_c    = (float*)alloc((size_t)CAP * HH * 4);
    prm.right_c   = (float*)alloc((size_t)CAP * HH * 4);
    prm.lepOut    = (float*)alloc((size_t)CAP * HH * 4);

    hipMemsetAsync(zbase, 0, zbytes, stream);
    hipMemsetAsync(fbase, 0x7f, fbytes, stream);   // firstL/firstH = huge

    setupA<<<NN / 128, 128, 0, stream>>>(prm);
    setupC<<<384, 256, 0, stream>>>(prm);

    for (int d = MAXD; d >= 1; --d) {
        s1_kernel<<<G_GATHER + CAP / 8, 128, 0, stream>>>(prm, d);
        s2_kernel<<<2 * (CAP / 8), 128, 0, stream>>>(prm, d);
    }
}